// Round 5
// baseline (328.241 us; speedup 1.0000x reference)
//
#include <hip/hip_runtime.h>
#include <hip/hip_bf16.h>
#include <math.h>

#define T_TOK 4096
#define DIM   1024
#define NEXP  8
#define DHID  4096
#define NDOUT 1024
#define BM    128
#define MAXTILES 40   // sum ceil(c_e/128) <= 32+7

typedef short bf16x8 __attribute__((ext_vector_type(8)));
typedef float f32x4 __attribute__((ext_vector_type(4)));

__device__ __forceinline__ unsigned short f2bf(float f) {
  unsigned u = __float_as_uint(f);
  u += 0x7fffu + ((u >> 16) & 1u);        // RNE
  return (unsigned short)(u >> 16);
}
__device__ __forceinline__ unsigned pack2bf(float a, float b) {
  return (unsigned)f2bf(a) | ((unsigned)f2bf(b) << 16);
}
__device__ __forceinline__ void gl_lds16(const void* g, void* l) {
  __builtin_amdgcn_global_load_lds(
      (const __attribute__((address_space(1))) void*)g,
      (__attribute__((address_space(3))) void*)l, 16, 0, 0);
}

// ---------------- gate: logits argmax (fp64 accum), 1 wave / token ----------
__global__ __launch_bounds__(256)
void gate_kernel(const float* __restrict__ x, const float* __restrict__ Wg,
                 const float* __restrict__ bg, int* __restrict__ sel) {
  int lane = threadIdx.x & 63;
  int wid  = threadIdx.x >> 6;
  int t = blockIdx.x * 4 + wid;
  if (t >= T_TOK) return;
  const float* xr = x + (size_t)t * DIM;
  double acc[NEXP];
#pragma unroll
  for (int e = 0; e < NEXP; e++) acc[e] = 0.0;
  for (int j = 0; j < DIM / 64; j++) {
    int d = lane + j * 64;
    float xv = xr[d];
    const float4* wr = reinterpret_cast<const float4*>(Wg + (size_t)d * NEXP);
    float4 w0 = wr[0], w1 = wr[1];
    acc[0] += (double)xv * (double)w0.x;
    acc[1] += (double)xv * (double)w0.y;
    acc[2] += (double)xv * (double)w0.z;
    acc[3] += (double)xv * (double)w0.w;
    acc[4] += (double)xv * (double)w1.x;
    acc[5] += (double)xv * (double)w1.y;
    acc[6] += (double)xv * (double)w1.z;
    acc[7] += (double)xv * (double)w1.w;
  }
#pragma unroll
  for (int off = 32; off >= 1; off >>= 1) {
#pragma unroll
    for (int e = 0; e < NEXP; e++) acc[e] += __shfl_down(acc[e], off);
  }
  if (lane == 0) {
    double best = acc[0] + (double)bg[0];
    int bi = 0;
#pragma unroll
    for (int e = 1; e < NEXP; e++) {
      double v = acc[e] + (double)bg[e];
      if (v > best) { best = v; bi = e; }
    }
    sel[t] = bi;
  }
}

// ---------------- routing bookkeeping ----------------
__global__ void zero_kernel(int* __restrict__ counts) {
  if (threadIdx.x < NEXP) counts[threadIdx.x] = 0;
}

__global__ void hist_kernel(const int* __restrict__ sel, int* __restrict__ counts) {
  __shared__ int lc[NEXP];
  if (threadIdx.x < NEXP) lc[threadIdx.x] = 0;
  __syncthreads();
  int t = blockIdx.x * 256 + threadIdx.x;
  atomicAdd(&lc[sel[t]], 1);
  __syncthreads();
  if (threadIdx.x < NEXP) atomicAdd(&counts[threadIdx.x], lc[threadIdx.x]);
}

__global__ void plan_kernel(const int* __restrict__ counts, int* __restrict__ base,
                            int* __restrict__ cursor, int* __restrict__ tileExpert,
                            int* __restrict__ tilePos, int* __restrict__ tileRows,
                            int* __restrict__ ntiles) {
  if (threadIdx.x == 0) {
    int acc = 0, nt = 0;
    for (int e = 0; e < NEXP; e++) {
      base[e] = acc; cursor[e] = acc;
      int c = counts[e];
      for (int j = 0; j < c; j += BM) {
        tileExpert[nt] = e;
        tilePos[nt]    = acc + j;
        int rem = c - j;
        tileRows[nt]   = rem < BM ? rem : BM;
        nt++;
      }
      acc += c;
    }
    *ntiles = nt;
  }
}

__global__ void scatter_kernel(const int* __restrict__ sel, int* __restrict__ cursor,
                               int* __restrict__ list) {
  __shared__ int lcnt[NEXP];
  __shared__ int lbase[NEXP];
  int tid = threadIdx.x;
  if (tid < NEXP) lcnt[tid] = 0;
  __syncthreads();
  int t = blockIdx.x * 256 + tid;
  int e = sel[t];
  int lpos = atomicAdd(&lcnt[e], 1);
  __syncthreads();
  if (tid < NEXP) lbase[tid] = atomicAdd(&cursor[tid], lcnt[tid]);
  __syncthreads();
  list[lbase[e] + lpos] = t;
}

// ---------------- conversions ----------------
__global__ __launch_bounds__(256)
void convert_x_kernel(const float* __restrict__ x, unsigned short* __restrict__ xbf) {
  int i = (blockIdx.x * 256 + threadIdx.x) * 8;
  float4 a = *(const float4*)(x + i);
  float4 b = *(const float4*)(x + i + 4);
  uint4 o;
  o.x = pack2bf(a.x, a.y); o.y = pack2bf(a.z, a.w);
  o.z = pack2bf(b.x, b.y); o.w = pack2bf(b.z, b.w);
  *(uint4*)(xbf + i) = o;
}

// [E][K][N] fp32 -> [E][N][K] bf16, 64x64 tiles via LDS
__global__ __launch_bounds__(256)
void transpose_convert_kernel(const float* __restrict__ in, unsigned short* __restrict__ out,
                              int K, int N) {
  int nb = blockIdx.x, kb = blockIdx.y, e = blockIdx.z;
  const float* inp = in + (size_t)e * K * N;
  unsigned short* outp = out + (size_t)e * N * K;
  __shared__ unsigned short lds[64][72];
  int tx = threadIdx.x;
  int kloc = tx >> 4;
  int n4   = (tx & 15) << 2;
#pragma unroll
  for (int p = 0; p < 4; p++) {
    int k = p * 16 + kloc;
    float4 v = *(const float4*)(inp + (size_t)(kb * 64 + k) * N + nb * 64 + n4);
    lds[n4 + 0][k] = f2bf(v.x);
    lds[n4 + 1][k] = f2bf(v.y);
    lds[n4 + 2][k] = f2bf(v.z);
    lds[n4 + 3][k] = f2bf(v.w);
  }
  __syncthreads();
  int n  = tx >> 2;
  int kq = (tx & 3) << 4;
  uint4 a = *(const uint4*)&lds[n][kq];
  uint4 b = *(const uint4*)&lds[n][kq + 8];
  unsigned short* o = outp + (size_t)(nb * 64 + n) * K + kb * 64 + kq;
  *(uint4*)o = a;
  *(uint4*)(o + 8) = b;
}

// ============ m97-style single-buffered 128x128 grouped GEMMs ============
// 256 thr = 4 waves (2x2), per-wave out 64x64. LDS 32 KiB (A 16K + B 16K)
// -> 4-5 blocks/CU; implicit cross-block overlap hides the barrier drain.
// T2 swizzle via pre-swizzled per-lane global source; LDS dest linear.
// Loop: STAGE(kt); sync (compiler drains vmcnt); compute(kt); sync.

__global__ __launch_bounds__(256)
void gemm1_kernel(const unsigned short* __restrict__ xbf, const unsigned short* __restrict__ W1T,
                  const float* __restrict__ b1, const int* __restrict__ list,
                  const int* __restrict__ tileExpert, const int* __restrict__ tilePos,
                  const int* __restrict__ tileRows, const int* __restrict__ ntiles,
                  unsigned short* __restrict__ Hc) {
  int tIdx = blockIdx.y;
  if (tIdx >= *ntiles) return;
  int e = tileExpert[tIdx], posBase = tilePos[tIdx], rows = tileRows[tIdx];
  int n0 = blockIdx.x * 128;

  __shared__ __align__(1024) char As[128 * 128];
  __shared__ __align__(1024) char Bs[128 * 128];

  const int tx = threadIdx.x, lane = tx & 63, w = tx >> 6;
  const int wm = w >> 1, wn = w & 1;
  const int rsub = lane >> 3;
  const int px = ((lane & 7) ^ rsub) << 4;

  const char* aS[4];
  const char* bS[4];
#pragma unroll
  for (int j = 0; j < 4; j++) {
    int r = w * 32 + j * 8 + rsub;
    int tok = list[posBase + (r < rows ? r : rows - 1)];
    aS[j] = (const char*)xbf + (size_t)tok * (DIM * 2) + px;
    bS[j] = (const char*)W1T + ((size_t)e * DHID + n0 + r) * (DIM * 2) + px;
  }

  f32x4 acc[4][4];
#pragma unroll
  for (int mf = 0; mf < 4; mf++)
#pragma unroll
    for (int nf = 0; nf < 4; nf++)
      acc[mf][nf] = f32x4{0.f, 0.f, 0.f, 0.f};

  const int NT = DIM / 64;   // 16
  for (int kt = 0; kt < NT; kt++) {
    int kb = kt * 128;
#pragma unroll
    for (int j = 0; j < 4; j++) {
      gl_lds16(aS[j] + kb, &As[(w * 32 + j * 8) * 128]);
      gl_lds16(bS[j] + kb, &Bs[(w * 32 + j * 8) * 128]);
    }
    __syncthreads();   // drains vmcnt -> staged data visible
#pragma unroll
    for (int ks = 0; ks < 2; ks++) {
      int koff = (ks * 64 + (lane >> 4) * 16) ^ ((lane & 7) << 4);
      bf16x8 aF[4], bF[4];
#pragma unroll
      for (int mf = 0; mf < 4; mf++)
        aF[mf] = *(const bf16x8*)&As[(wm * 64 + mf * 16 + (lane & 15)) * 128 + koff];
#pragma unroll
      for (int nf = 0; nf < 4; nf++)
        bF[nf] = *(const bf16x8*)&Bs[(wn * 64 + nf * 16 + (lane & 15)) * 128 + koff];
#pragma unroll
      for (int mf = 0; mf < 4; mf++)
#pragma unroll
        for (int nf = 0; nf < 4; nf++)
          acc[mf][nf] = __builtin_amdgcn_mfma_f32_16x16x32_bf16(aF[mf], bF[nf], acc[mf][nf], 0, 0, 0);
    }
    __syncthreads();   // readers done before next overwrite
  }

  const float* b1e = b1 + (size_t)e * DHID;
#pragma unroll
  for (int nf = 0; nf < 4; nf++) {
    int col = n0 + wn * 64 + nf * 16 + (lane & 15);
    float bias = b1e[col];
#pragma unroll
    for (int mf = 0; mf < 4; mf++) {
#pragma unroll
      for (int j = 0; j < 4; j++) {
        int rloc = wm * 64 + mf * 16 + ((lane >> 4) << 2) + j;
        if (rloc < rows) {
          float h = acc[mf][nf][j] + bias;
          float g = 0.5f * h * (1.0f + erff(h * 0.70710678118654752f));
          Hc[(size_t)(posBase + rloc) * DHID + col] = f2bf(g);
        }
      }
    }
  }
}

// GEMM2 split-K=2: z covers k in [z*2048, z*2048+2048). fp32 partials, bias in z=0.
__global__ __launch_bounds__(256)
void gemm2_kernel(const unsigned short* __restrict__ Hc, const unsigned short* __restrict__ W2T,
                  const float* __restrict__ b2, const int* __restrict__ tileExpert,
                  const int* __restrict__ tilePos, const int* __restrict__ tileRows,
                  const int* __restrict__ ntiles, float* __restrict__ Ppart) {
  int tIdx = blockIdx.y;
  if (tIdx >= *ntiles) return;
  int e = tileExpert[tIdx], posBase = tilePos[tIdx], rows = tileRows[tIdx];
  int n0 = blockIdx.x * 128;
  int zs = blockIdx.z;
  size_t kbyte0 = (size_t)zs * 32 * 128;   // 32 K-tiles per split

  __shared__ __align__(1024) char As[128 * 128];
  __shared__ __align__(1024) char Bs[128 * 128];

  const int tx = threadIdx.x, lane = tx & 63, w = tx >> 6;
  const int wm = w >> 1, wn = w & 1;
  const int rsub = lane >> 3;
  const int px = ((lane & 7) ^ rsub) << 4;

  const char* aS[4];
  const char* bS[4];
#pragma unroll
  for (int j = 0; j < 4; j++) {
    int r = w * 32 + j * 8 + rsub;
    int ar = posBase + (r < rows ? r : rows - 1);
    aS[j] = (const char*)Hc + (size_t)ar * (DHID * 2) + kbyte0 + px;
    bS[j] = (const char*)W2T + ((size_t)e * NDOUT + n0 + r) * (DHID * 2) + kbyte0 + px;
  }

  f32x4 acc[4][4];
#pragma unroll
  for (int mf = 0; mf < 4; mf++)
#pragma unroll
    for (int nf = 0; nf < 4; nf++)
      acc[mf][nf] = f32x4{0.f, 0.f, 0.f, 0.f};

  const int NT = 32;
  for (int kt = 0; kt < NT; kt++) {
    int kb = kt * 128;
#pragma unroll
    for (int j = 0; j < 4; j++) {
      gl_lds16(aS[j] + kb, &As[(w * 32 + j * 8) * 128]);
      gl_lds16(bS[j] + kb, &Bs[(w * 32 + j * 8) * 128]);
    }
    __syncthreads();
#pragma unroll
    for (int ks = 0; ks < 2; ks++) {
      int koff = (ks * 64 + (lane >> 4) * 16) ^ ((lane & 7) << 4);
      bf16x8 aF[4], bF[4];
#pragma unroll
      for (int mf = 0; mf < 4; mf++)
        aF[mf] = *(const bf16x8*)&As[(wm * 64 + mf * 16 + (lane & 15)) * 128 + koff];
#pragma unroll
      for (int nf = 0; nf < 4; nf++)
        bF[nf] = *(const bf16x8*)&Bs[(wn * 64 + nf * 16 + (lane & 15)) * 128 + koff];
#pragma unroll
      for (int mf = 0; mf < 4; mf++)
#pragma unroll
        for (int nf = 0; nf < 4; nf++)
          acc[mf][nf] = __builtin_amdgcn_mfma_f32_16x16x32_bf16(aF[mf], bF[nf], acc[mf][nf], 0, 0, 0);
    }
    __syncthreads();
  }

  const float* b2e = b2 + (size_t)e * NDOUT;
  float* P = Ppart + (size_t)zs * T_TOK * NDOUT;
#pragma unroll
  for (int nf = 0; nf < 4; nf++) {
    int col = n0 + wn * 64 + nf * 16 + (lane & 15);
    float bias = (zs == 0) ? b2e[col] : 0.f;
#pragma unroll
    for (int mf = 0; mf < 4; mf++)
#pragma unroll
      for (int j = 0; j < 4; j++) {
        int rloc = wm * 64 + mf * 16 + ((lane >> 4) << 2) + j;
        if (rloc < rows)
          P[(size_t)(posBase + rloc) * NDOUT + col] = acc[mf][nf][j] + bias;
      }
  }
}

// out[list[pos]] = P0[pos] + P1[pos]   (bias already in P0)
__global__ __launch_bounds__(256)
void reduce_kernel(const float* __restrict__ Ppart, const int* __restrict__ list,
                   float* __restrict__ out) {
  int pos = blockIdx.x;
  int tok = list[pos];
  int c = threadIdx.x * 4;
  float4 a = *(const float4*)(Ppart + (size_t)pos * NDOUT + c);
  float4 b = *(const float4*)(Ppart + (size_t)T_TOK * NDOUT + (size_t)pos * NDOUT + c);
  float4 o; o.x = a.x + b.x; o.y = a.y + b.y; o.z = a.z + b.z; o.w = a.w + b.w;
  *(float4*)(out + (size_t)tok * NDOUT + c) = o;
}

// ---------------- launch ----------------
extern "C" void kernel_launch(void* const* d_in, const int* in_sizes, int n_in,
                              void* d_out, int out_size, void* d_ws, size_t ws_size,
                              hipStream_t stream) {
  const float* x  = (const float*)d_in[0];
  const float* Wg = (const float*)d_in[1];
  const float* bg = (const float*)d_in[2];
  const float* W1 = (const float*)d_in[3];
  const float* b1 = (const float*)d_in[4];
  const float* W2 = (const float*)d_in[5];
  const float* b2 = (const float*)d_in[6];
  float* out = (float*)d_out;

  char* ws = (char*)d_ws;
  int* sel        = (int*)(ws);
  int* counts     = (int*)(ws + 16384);
  int* base       = (int*)(ws + 16448);
  int* cursor     = (int*)(ws + 16512);
  int* ntiles     = (int*)(ws + 16576);
  int* tileExpert = (int*)(ws + 16640);
  int* tilePos    = (int*)(ws + 16832);
  int* tileRows   = (int*)(ws + 17024);
  int* list       = (int*)(ws + 17408);

  unsigned short* xbf = (unsigned short*)(ws + (1ull << 20));    // 8 MB
  unsigned short* Hc  = (unsigned short*)(ws + (16ull << 20));   // 32 MB
  unsigned short* W1T = (unsigned short*)(ws + (48ull << 20));   // 64 MB [E][DH][DIM]
  unsigned short* W2T = (unsigned short*)(ws + (112ull << 20));  // 64 MB [E][DOUT][DH]
  float* Ppart        = (float*)(ws + (48ull << 20));            // reuse W1T region (2x16 MB)

  gate_kernel<<<T_TOK / 4, 256, 0, stream>>>(x, Wg, bg, sel);
  zero_kernel<<<1, 64, 0, stream>>>(counts);
  hist_kernel<<<T_TOK / 256, 256, 0, stream>>>(sel, counts);
  plan_kernel<<<1, 64, 0, stream>>>(counts, base, cursor, tileExpert, tilePos, tileRows, ntiles);
  scatter_kernel<<<T_TOK / 256, 256, 0, stream>>>(sel, cursor, list);

  convert_x_kernel<<<T_TOK * DIM / (256 * 8), 256, 0, stream>>>(x, xbf);
  transpose_convert_kernel<<<dim3(DHID / 64, DIM / 64, NEXP), 256, 0, stream>>>(W1, W1T, DIM, DHID);
  transpose_convert_kernel<<<dim3(NDOUT / 64, DHID / 64, NEXP), 256, 0, stream>>>(W2, W2T, DHID, NDOUT);

  gemm1_kernel<<<dim3(DHID / 128, MAXTILES), 256, 0, stream>>>(
      xbf, W1T, b1, list, tileExpert, tilePos, tileRows, ntiles, Hc);
  gemm2_kernel<<<dim3(NDOUT / 128, MAXTILES, 2), 256, 0, stream>>>(
      Hc, W2T, b2, tileExpert, tilePos, tileRows, ntiles, Ppart);
  reduce_kernel<<<T_TOK, 256, 0, stream>>>(Ppart, list, out);
}

// Round 6
// 307.516 us; speedup vs baseline: 1.0674x; 1.0674x over previous
//
#include <hip/hip_runtime.h>
#include <hip/hip_bf16.h>
#include <math.h>

#define T_TOK 4096
#define DIM   1024
#define NEXP  8
#define DHID  4096
#define NDOUT 1024
#define BM    128
#define MAXTILES 40   // sum ceil(c_e/128) <= 32+7

typedef short bf16x8 __attribute__((ext_vector_type(8)));
typedef float f32x4 __attribute__((ext_vector_type(4)));

__device__ __forceinline__ unsigned short f2bf(float f) {
  unsigned u = __float_as_uint(f);
  u += 0x7fffu + ((u >> 16) & 1u);        // RNE
  return (unsigned short)(u >> 16);
}
__device__ __forceinline__ unsigned pack2bf(float a, float b) {
  return (unsigned)f2bf(a) | ((unsigned)f2bf(b) << 16);
}
__device__ __forceinline__ void gl_lds16(const void* g, void* l) {
  __builtin_amdgcn_global_load_lds(
      (const __attribute__((address_space(1))) void*)g,
      (__attribute__((address_space(3))) void*)l, 16, 0, 0);
}

// ---------------- gate: logits argmax (fp64 accum), 1 wave / token ----------
__global__ __launch_bounds__(256)
void gate_kernel(const float* __restrict__ x, const float* __restrict__ Wg,
                 const float* __restrict__ bg, int* __restrict__ sel) {
  int lane = threadIdx.x & 63;
  int wid  = threadIdx.x >> 6;
  int t = blockIdx.x * 4 + wid;
  if (t >= T_TOK) return;
  const float* xr = x + (size_t)t * DIM;
  double acc[NEXP];
#pragma unroll
  for (int e = 0; e < NEXP; e++) acc[e] = 0.0;
  for (int j = 0; j < DIM / 64; j++) {
    int d = lane + j * 64;
    float xv = xr[d];
    const float4* wr = reinterpret_cast<const float4*>(Wg + (size_t)d * NEXP);
    float4 w0 = wr[0], w1 = wr[1];
    acc[0] += (double)xv * (double)w0.x;
    acc[1] += (double)xv * (double)w0.y;
    acc[2] += (double)xv * (double)w0.z;
    acc[3] += (double)xv * (double)w0.w;
    acc[4] += (double)xv * (double)w1.x;
    acc[5] += (double)xv * (double)w1.y;
    acc[6] += (double)xv * (double)w1.z;
    acc[7] += (double)xv * (double)w1.w;
  }
#pragma unroll
  for (int off = 32; off >= 1; off >>= 1) {
#pragma unroll
    for (int e = 0; e < NEXP; e++) acc[e] += __shfl_down(acc[e], off);
  }
  if (lane == 0) {
    double best = acc[0] + (double)bg[0];
    int bi = 0;
#pragma unroll
    for (int e = 1; e < NEXP; e++) {
      double v = acc[e] + (double)bg[e];
      if (v > best) { best = v; bi = e; }
    }
    sel[t] = bi;
  }
}

// ---------------- routing bookkeeping ----------------
__global__ void zero_kernel(int* __restrict__ counts) {
  if (threadIdx.x < NEXP) counts[threadIdx.x] = 0;
}

__global__ void hist_kernel(const int* __restrict__ sel, int* __restrict__ counts) {
  __shared__ int lc[NEXP];
  if (threadIdx.x < NEXP) lc[threadIdx.x] = 0;
  __syncthreads();
  int t = blockIdx.x * 256 + threadIdx.x;
  atomicAdd(&lc[sel[t]], 1);
  __syncthreads();
  if (threadIdx.x < NEXP) atomicAdd(&counts[threadIdx.x], lc[threadIdx.x]);
}

__global__ void plan_kernel(const int* __restrict__ counts, int* __restrict__ base,
                            int* __restrict__ cursor, int* __restrict__ tileExpert,
                            int* __restrict__ tilePos, int* __restrict__ tileRows,
                            int* __restrict__ ntiles) {
  if (threadIdx.x == 0) {
    int acc = 0, nt = 0;
    for (int e = 0; e < NEXP; e++) {
      base[e] = acc; cursor[e] = acc;
      int c = counts[e];
      for (int j = 0; j < c; j += BM) {
        tileExpert[nt] = e;
        tilePos[nt]    = acc + j;
        int rem = c - j;
        tileRows[nt]   = rem < BM ? rem : BM;
        nt++;
      }
      acc += c;
    }
    *ntiles = nt;
  }
}

__global__ void scatter_kernel(const int* __restrict__ sel, int* __restrict__ cursor,
                               int* __restrict__ list) {
  __shared__ int lcnt[NEXP];
  __shared__ int lbase[NEXP];
  int tid = threadIdx.x;
  if (tid < NEXP) lcnt[tid] = 0;
  __syncthreads();
  int t = blockIdx.x * 256 + tid;
  int e = sel[t];
  int lpos = atomicAdd(&lcnt[e], 1);
  __syncthreads();
  if (tid < NEXP) lbase[tid] = atomicAdd(&cursor[tid], lcnt[tid]);
  __syncthreads();
  list[lbase[e] + lpos] = t;
}

// ---------------- conversions ----------------
__global__ __launch_bounds__(256)
void convert_x_kernel(const float* __restrict__ x, unsigned short* __restrict__ xbf) {
  int i = (blockIdx.x * 256 + threadIdx.x) * 8;
  float4 a = *(const float4*)(x + i);
  float4 b = *(const float4*)(x + i + 4);
  uint4 o;
  o.x = pack2bf(a.x, a.y); o.y = pack2bf(a.z, a.w);
  o.z = pack2bf(b.x, b.y); o.w = pack2bf(b.z, b.w);
  *(uint4*)(xbf + i) = o;
}

// [E][K][N] fp32 -> tiled swizzled bf16: [E][N/128][K/64] tiles of 16KB whose
// byte order equals the GEMM's desired LDS image:
//   tile_byte[r*128 + (2k ^ ((r&7)<<4))] = elem(n-row r, k-col k)
// GEMM then stages a tile LINEARLY (1KB contiguous per gl_lds16) and applies
// the same XOR on the LDS read side.
__global__ __launch_bounds__(256)
void transpose_tile_kernel(const float* __restrict__ in, unsigned short* __restrict__ out,
                           int K, int N) {
  int nb = blockIdx.x, kb = blockIdx.y, e = blockIdx.z;
  const float* inp = in + (size_t)e * K * N;
  __shared__ unsigned short lds[128][72];
  int tx = threadIdx.x;
  // read: 64 k-rows x 128 n-cols fp32, coalesced along n
  int kloc = tx >> 5;            // 0..7
  int n4   = (tx & 31) << 2;     // 0..124
#pragma unroll
  for (int p = 0; p < 8; p++) {
    int k = p * 8 + kloc;
    float4 v = *(const float4*)(inp + (size_t)(kb * 64 + k) * N + nb * 128 + n4);
    lds[n4 + 0][k] = f2bf(v.x);
    lds[n4 + 1][k] = f2bf(v.y);
    lds[n4 + 2][k] = f2bf(v.z);
    lds[n4 + 3][k] = f2bf(v.w);
  }
  __syncthreads();
  // write: swizzled 16B chunks, contiguous 16KB tile
  char* tile = (char*)(out + (((size_t)e * gridDim.x + nb) * gridDim.y + kb) * 8192);
  int r  = tx >> 1;
  int kc0 = (tx & 1) * 32;
#pragma unroll
  for (int c = 0; c < 4; c++) {
    int kc = kc0 + c * 8;
    uint4 v = *(const uint4*)&lds[r][kc];
    *(uint4*)(tile + r * 128 + ((2 * kc) ^ ((r & 7) << 4))) = v;
  }
}

// ============ m97-style single-buffered 128x128 grouped GEMMs ============
// 256 thr = 4 waves (2x2), per-wave out 64x64, 32 KiB LDS.
// B (and gemm2's A) come from tiled swizzled images -> every gl_lds16 reads
// 1KB contiguous; per K-tile 16KB contiguous per operand. A of gemm1 is the
// token-gathered xbf (row-major, pre-swizzled per-lane source).

__global__ __launch_bounds__(256)
void gemm1_kernel(const unsigned short* __restrict__ xbf, const unsigned short* __restrict__ W1T,
                  const float* __restrict__ b1, const int* __restrict__ list,
                  const int* __restrict__ tileExpert, const int* __restrict__ tilePos,
                  const int* __restrict__ tileRows, const int* __restrict__ ntiles,
                  unsigned short* __restrict__ HcT) {
  int tIdx = blockIdx.y;
  if (tIdx >= *ntiles) return;
  int e = tileExpert[tIdx], posBase = tilePos[tIdx], rows = tileRows[tIdx];
  int nb = blockIdx.x;             // n-block: cols [nb*128, nb*128+128)

  __shared__ __align__(1024) char As[128 * 128];
  __shared__ __align__(1024) char Bs[128 * 128];

  const int tx = threadIdx.x, lane = tx & 63, w = tx >> 6;
  const int wm = w >> 1, wn = w & 1;
  const int rsub = lane >> 3;
  const int px = ((lane & 7) ^ rsub) << 4;   // pre-swizzled source for row-major A

  const char* aS[4];
#pragma unroll
  for (int j = 0; j < 4; j++) {
    int r = w * 32 + j * 8 + rsub;
    int tok = list[posBase + (r < rows ? r : rows - 1)];
    aS[j] = (const char*)xbf + (size_t)tok * (DIM * 2) + px;
  }
  // B: tiled image [E][32 nb][16 kt][16KB]; per-lane source is LINEAR
  const char* bTile = (const char*)W1T + (((size_t)e * (DHID / 128) + nb) * (DIM / 64)) * 16384
                      + w * 4096 + lane * 16;

  f32x4 acc[4][4];
#pragma unroll
  for (int mf = 0; mf < 4; mf++)
#pragma unroll
    for (int nf = 0; nf < 4; nf++)
      acc[mf][nf] = f32x4{0.f, 0.f, 0.f, 0.f};

  const int NT = DIM / 64;   // 16
  for (int kt = 0; kt < NT; kt++) {
#pragma unroll
    for (int j = 0; j < 4; j++) {
      gl_lds16(aS[j] + kt * 128, &As[(w * 32 + j * 8) * 128]);
      gl_lds16(bTile + kt * 16384 + j * 1024, &Bs[w * 4096 + j * 1024]);
    }
    __syncthreads();   // drains vmcnt -> staged data visible
#pragma unroll
    for (int ks = 0; ks < 2; ks++) {
      int koff = (ks * 64 + (lane >> 4) * 16) ^ ((lane & 7) << 4);
      bf16x8 aF[4], bF[4];
#pragma unroll
      for (int mf = 0; mf < 4; mf++)
        aF[mf] = *(const bf16x8*)&As[(wm * 64 + mf * 16 + (lane & 15)) * 128 + koff];
#pragma unroll
      for (int nf = 0; nf < 4; nf++)
        bF[nf] = *(const bf16x8*)&Bs[(wn * 64 + nf * 16 + (lane & 15)) * 128 + koff];
#pragma unroll
      for (int mf = 0; mf < 4; mf++)
#pragma unroll
        for (int nf = 0; nf < 4; nf++)
          acc[mf][nf] = __builtin_amdgcn_mfma_f32_16x16x32_bf16(aF[mf], bF[nf], acc[mf][nf], 0, 0, 0);
    }
    __syncthreads();   // readers done before next overwrite
  }

  // Epilogue: bias + gelu, write Hc as tiled swizzled image for gemm2's A:
  // HcT[tIdx][kt2 = col/64][128 r][64 k] with the same XOR layout.
  // Write ALL 128 rows (clamped rows duplicate real tokens; finite).
  const float* b1e = b1 + (size_t)e * DHID;
  char* hBase = (char*)(HcT + (size_t)tIdx * (DHID / 64) * 8192);
#pragma unroll
  for (int nf = 0; nf < 4; nf++) {
    int col = nb * 128 + wn * 64 + nf * 16 + (lane & 15);
    int kt2 = col >> 6;
    int colk2 = (col & 63) * 2;
    float bias = b1e[col];
    char* tile = hBase + (size_t)kt2 * 16384;
#pragma unroll
    for (int mf = 0; mf < 4; mf++) {
#pragma unroll
      for (int j = 0; j < 4; j++) {
        int r = wm * 64 + mf * 16 + ((lane >> 4) << 2) + j;
        float h = acc[mf][nf][j] + bias;
        float g = 0.5f * h * (1.0f + erff(h * 0.70710678118654752f));
        *(unsigned short*)(tile + r * 128 + (colk2 ^ ((r & 7) << 4))) = f2bf(g);
      }
    }
  }
}

// GEMM2 split-K=2: z covers K-tiles [z*32, z*32+32). fp32 partials, bias in z=0.
// A = HcT tiled image (linear staging), B = W2T tiled image (linear staging).
__global__ __launch_bounds__(256)
void gemm2_kernel(const unsigned short* __restrict__ HcT, const unsigned short* __restrict__ W2T,
                  const float* __restrict__ b2, const int* __restrict__ tileExpert,
                  const int* __restrict__ tilePos, const int* __restrict__ tileRows,
                  const int* __restrict__ ntiles, float* __restrict__ Ppart) {
  int tIdx = blockIdx.y;
  if (tIdx >= *ntiles) return;
  int e = tileExpert[tIdx], posBase = tilePos[tIdx], rows = tileRows[tIdx];
  int nb = blockIdx.x;
  int zs = blockIdx.z;

  __shared__ __align__(1024) char As[128 * 128];
  __shared__ __align__(1024) char Bs[128 * 128];

  const int tx = threadIdx.x, lane = tx & 63, w = tx >> 6;
  const int wm = w >> 1, wn = w & 1;

  const char* aTile = (const char*)HcT + (size_t)tIdx * (DHID / 64) * 16384
                      + (size_t)zs * 32 * 16384 + w * 4096 + lane * 16;
  const char* bTile = (const char*)W2T + (((size_t)e * (NDOUT / 128) + nb) * (DHID / 64)) * 16384
                      + (size_t)zs * 32 * 16384 + w * 4096 + lane * 16;

  f32x4 acc[4][4];
#pragma unroll
  for (int mf = 0; mf < 4; mf++)
#pragma unroll
    for (int nf = 0; nf < 4; nf++)
      acc[mf][nf] = f32x4{0.f, 0.f, 0.f, 0.f};

  const int NT = 32;
  for (int kt = 0; kt < NT; kt++) {
#pragma unroll
    for (int j = 0; j < 4; j++) {
      gl_lds16(aTile + kt * 16384 + j * 1024, &As[w * 4096 + j * 1024]);
      gl_lds16(bTile + kt * 16384 + j * 1024, &Bs[w * 4096 + j * 1024]);
    }
    __syncthreads();
#pragma unroll
    for (int ks = 0; ks < 2; ks++) {
      int koff = (ks * 64 + (lane >> 4) * 16) ^ ((lane & 7) << 4);
      bf16x8 aF[4], bF[4];
#pragma unroll
      for (int mf = 0; mf < 4; mf++)
        aF[mf] = *(const bf16x8*)&As[(wm * 64 + mf * 16 + (lane & 15)) * 128 + koff];
#pragma unroll
      for (int nf = 0; nf < 4; nf++)
        bF[nf] = *(const bf16x8*)&Bs[(wn * 64 + nf * 16 + (lane & 15)) * 128 + koff];
#pragma unroll
      for (int mf = 0; mf < 4; mf++)
#pragma unroll
        for (int nf = 0; nf < 4; nf++)
          acc[mf][nf] = __builtin_amdgcn_mfma_f32_16x16x32_bf16(aF[mf], bF[nf], acc[mf][nf], 0, 0, 0);
    }
    __syncthreads();
  }

  const float* b2e = b2 + (size_t)e * NDOUT;
  float* P = Ppart + (size_t)zs * T_TOK * NDOUT;
#pragma unroll
  for (int nf = 0; nf < 4; nf++) {
    int col = nb * 128 + wn * 64 + nf * 16 + (lane & 15);
    float bias = (zs == 0) ? b2e[col] : 0.f;
#pragma unroll
    for (int mf = 0; mf < 4; mf++)
#pragma unroll
      for (int j = 0; j < 4; j++) {
        int rloc = wm * 64 + mf * 16 + ((lane >> 4) << 2) + j;
        if (rloc < rows)
          P[(size_t)(posBase + rloc) * NDOUT + col] = acc[mf][nf][j] + bias;
      }
  }
}

// out[list[pos]] = P0[pos] + P1[pos]   (bias already in P0)
__global__ __launch_bounds__(256)
void reduce_kernel(const float* __restrict__ Ppart, const int* __restrict__ list,
                   float* __restrict__ out) {
  int pos = blockIdx.x;
  int tok = list[pos];
  int c = threadIdx.x * 4;
  float4 a = *(const float4*)(Ppart + (size_t)pos * NDOUT + c);
  float4 b = *(const float4*)(Ppart + (size_t)T_TOK * NDOUT + (size_t)pos * NDOUT + c);
  float4 o; o.x = a.x + b.x; o.y = a.y + b.y; o.z = a.z + b.z; o.w = a.w + b.w;
  *(float4*)(out + (size_t)tok * NDOUT + c) = o;
}

// ---------------- launch ----------------
extern "C" void kernel_launch(void* const* d_in, const int* in_sizes, int n_in,
                              void* d_out, int out_size, void* d_ws, size_t ws_size,
                              hipStream_t stream) {
  const float* x  = (const float*)d_in[0];
  const float* Wg = (const float*)d_in[1];
  const float* bg = (const float*)d_in[2];
  const float* W1 = (const float*)d_in[3];
  const float* b1 = (const float*)d_in[4];
  const float* W2 = (const float*)d_in[5];
  const float* b2 = (const float*)d_in[6];
  float* out = (float*)d_out;

  char* ws = (char*)d_ws;
  int* sel        = (int*)(ws);
  int* counts     = (int*)(ws + 16384);
  int* base       = (int*)(ws + 16448);
  int* cursor     = (int*)(ws + 16512);
  int* ntiles     = (int*)(ws + 16576);
  int* tileExpert = (int*)(ws + 16640);
  int* tilePos    = (int*)(ws + 16832);
  int* tileRows   = (int*)(ws + 17024);
  int* list       = (int*)(ws + 17408);

  unsigned short* xbf = (unsigned short*)(ws + (1ull << 20));    // 8 MB
  unsigned short* HcT = (unsigned short*)(ws + (10ull << 20));   // 40 MB tiled Hc
  unsigned short* W1T = (unsigned short*)(ws + (52ull << 20));   // 64 MB tiled
  unsigned short* W2T = (unsigned short*)(ws + (116ull << 20));  // 64 MB tiled
  float* Ppart        = (float*)(ws + (52ull << 20));            // reuse W1T region (2x16 MB)

  gate_kernel<<<T_TOK / 4, 256, 0, stream>>>(x, Wg, bg, sel);
  zero_kernel<<<1, 64, 0, stream>>>(counts);
  hist_kernel<<<T_TOK / 256, 256, 0, stream>>>(sel, counts);
  plan_kernel<<<1, 64, 0, stream>>>(counts, base, cursor, tileExpert, tilePos, tileRows, ntiles);
  scatter_kernel<<<T_TOK / 256, 256, 0, stream>>>(sel, cursor, list);

  convert_x_kernel<<<T_TOK * DIM / (256 * 8), 256, 0, stream>>>(x, xbf);
  // W1: K=DIM, N=DHID -> grid (N/128=32, K/64=16, E)
  transpose_tile_kernel<<<dim3(DHID / 128, DIM / 64, NEXP), 256, 0, stream>>>(W1, W1T, DIM, DHID);
  // W2: K=DHID, N=NDOUT -> grid (N/128=8, K/64=64, E)
  transpose_tile_kernel<<<dim3(NDOUT / 128, DHID / 64, NEXP), 256, 0, stream>>>(W2, W2T, DHID, NDOUT);

  gemm1_kernel<<<dim3(DHID / 128, MAXTILES), 256, 0, stream>>>(
      xbf, W1T, b1, list, tileExpert, tilePos, tileRows, ntiles, HcT);
  gemm2_kernel<<<dim3(NDOUT / 128, MAXTILES, 2), 256, 0, stream>>>(
      HcT, W2T, b2, tileExpert, tilePos, tileRows, ntiles, Ppart);
  reduce_kernel<<<T_TOK, 256, 0, stream>>>(Ppart, list, out);
}